// Round 4
// baseline (215.328 us; speedup 1.0000x reference)
//
#include <hip/hip_runtime.h>
#include <math.h>

#define D 2048
#define EPS_COS 1e-8f
#define EPS_DEN 1e-6f
#define INV_TEMP 10.0f
#define TPB 256
#define WPB 4                  // waves per block
#define NSLOT 64               // spread denominator slots (contention-free)

// pos_pair: reference declares int64 but JAX x64-off makes it int32.
// Hedge: accept int32 reading iff plausible (in range, i != j), else int64.
__device__ __forceinline__ void get_ij(const int* __restrict__ p, int n,
                                       int& i, int& j) {
    int i32 = p[0], j32 = p[1];
    if (i32 >= 0 && i32 < n && j32 >= 0 && j32 < n && i32 != j32) {
        i = i32; j = j32; return;
    }
    const long long* p64 = (const long long*)p;
    i = (int)p64[0]; j = (int)p64[1];
}

// Single fused kernel. Wave-per-2-rows streaming (same as R3), then:
//  - per-block LDS reduce of denominator partial (+ e_j if owned)
//  - block thread 0: atomicAdd partial into accf[blockIdx.x & 63]
//    (device-scope, returning form: consuming the result forces
//    s_waitcnt vmcnt(0) => add performed at coherence point)
//  - atomicAdd done-counter; last block coherently reads 65 slots, finishes.
// NO fences anywhere (R2's __threadfence was the 147us pathology).
__global__ __launch_bounds__(TPB)
void fused_kernel(const float* __restrict__ x, const int* __restrict__ pos,
                  float* __restrict__ out, float* __restrict__ accf,
                  unsigned* __restrict__ accu, int n, int nblocks) {
    int i, j;
    get_ij(pos, n, i, j);
    const int lane  = threadIdx.x & 63;
    const int wave  = threadIdx.x >> 6;
    const int gwave = blockIdx.x * WPB + wave;
    const int row0  = gwave * 2;
    const bool v0 = (row0     < n);
    const bool v1 = (row0 + 1 < n);
    const int  r0 = v0 ? row0     : 0;
    const int  r1 = v1 ? row0 + 1 : 0;

    // xi slice in registers (8 float4 = 32 VGPR); L1-resident broadcast
    const float4* __restrict__ xi = (const float4*)(x + (size_t)i * D);
    float4 b[8];
#pragma unroll
    for (int w = 0; w < 8; ++w) b[w] = xi[lane + w * 64];

    float sqi = 0.f;
#pragma unroll
    for (int w = 0; w < 8; ++w)
        sqi = fmaf(b[w].x, b[w].x, fmaf(b[w].y, b[w].y,
              fmaf(b[w].z, b[w].z, fmaf(b[w].w, b[w].w, sqi))));
#pragma unroll
    for (int off = 32; off; off >>= 1) sqi += __shfl_down(sqi, off);
    const float ni = fmaxf(sqrtf(sqi), EPS_COS);   // valid in lane 0

    // stream both rows with 16 float4 in flight per lane
    const float4* __restrict__ p0 = (const float4*)(x + (size_t)r0 * D);
    const float4* __restrict__ p1 = (const float4*)(x + (size_t)r1 * D);
    float4 a0[8], a1[8];
#pragma unroll
    for (int w = 0; w < 8; ++w) a0[w] = p0[lane + w * 64];
#pragma unroll
    for (int w = 0; w < 8; ++w) a1[w] = p1[lane + w * 64];

    float d0 = 0.f, s0 = 0.f, d1 = 0.f, s1 = 0.f;
#pragma unroll
    for (int w = 0; w < 8; ++w) {
        d0 = fmaf(a0[w].x, b[w].x, fmaf(a0[w].y, b[w].y,
             fmaf(a0[w].z, b[w].z, fmaf(a0[w].w, b[w].w, d0))));
        s0 = fmaf(a0[w].x, a0[w].x, fmaf(a0[w].y, a0[w].y,
             fmaf(a0[w].z, a0[w].z, fmaf(a0[w].w, a0[w].w, s0))));
        d1 = fmaf(a1[w].x, b[w].x, fmaf(a1[w].y, b[w].y,
             fmaf(a1[w].z, b[w].z, fmaf(a1[w].w, b[w].w, d1))));
        s1 = fmaf(a1[w].x, a1[w].x, fmaf(a1[w].y, a1[w].y,
             fmaf(a1[w].z, a1[w].z, fmaf(a1[w].w, a1[w].w, s1))));
    }
#pragma unroll
    for (int off = 32; off; off >>= 1) {
        d0 += __shfl_down(d0, off);
        s0 += __shfl_down(s0, off);
        d1 += __shfl_down(d1, off);
        s1 += __shfl_down(s1, off);
    }

    __shared__ float s_den[WPB], s_ej[WPB];
    if (lane == 0) {
        float e0 = v0 ? expf(INV_TEMP * d0 / (fmaxf(sqrtf(s0), EPS_COS) * ni)) : 0.f;
        float e1 = v1 ? expf(INV_TEMP * d1 / (fmaxf(sqrtf(s1), EPS_COS) * ni)) : 0.f;
        float den = 0.f;
        if (v0 && r0 != i) den += e0;           // den includes k==j, excludes k==i
        if (v1 && r1 != i) den += e1;
        s_den[wave] = den;
        s_ej[wave]  = (v0 && r0 == j) ? e0 : ((v1 && r1 == j) ? e1 : 0.f);
    }
    __syncthreads();

    if (threadIdx.x == 0) {
        float bden = s_den[0] + s_den[1] + s_den[2] + s_den[3];
        float bej  = s_ej[0]  + s_ej[1]  + s_ej[2]  + s_ej[3];
        float r  = atomicAdd(&accf[blockIdx.x & (NSLOT - 1)], bden);
        float r2 = (bej != 0.f) ? atomicAdd(&accf[NSLOT], bej) : 0.f;
        // force completion-at-coherence-point before signaling: consume the
        // returned values (data dep => compiler waits) + explicit waitcnt.
        unsigned inc = 1u
            + ((__float_as_uint(r)  == 0x7F800001u) ? 1u : 0u)   // never true
            + ((__float_as_uint(r2) == 0x7F800001u) ? 1u : 0u);  // never true
        asm volatile("s_waitcnt vmcnt(0)" ::: "memory");
        unsigned old = atomicAdd(accu, inc);
        if (old == (unsigned)(nblocks - 1)) {   // last block finishes the loss
            float den = 0.f;
#pragma unroll
            for (int s = 0; s < NSLOT; ++s) den += atomicAdd(&accf[s], 0.f);
            float nom = atomicAdd(&accf[NSLOT], 0.f);
            out[0] = -logf(nom / (den + EPS_DEN));
        }
    }
}

extern "C" void kernel_launch(void* const* d_in, const int* in_sizes, int n_in,
                              void* d_out, int out_size, void* d_ws, size_t ws_size,
                              hipStream_t stream) {
    const float* x   = (const float*)d_in[0];
    const int*   pos = (const int*)d_in[1];
    float*       out = (float*)d_out;
    float*       accf = (float*)d_ws;                    // [0..63] den, [64] nom
    unsigned*    accu = (unsigned*)d_ws + NSLOT + 1;     // done counter

    const int n = in_sizes[0] / D;                       // 16384
    const int rows_per_block = WPB * 2;
    const int nblocks = (n + rows_per_block - 1) / rows_per_block;  // 2048

    hipMemsetAsync(d_ws, 0, (NSLOT + 2) * sizeof(float), stream);
    fused_kernel<<<nblocks, TPB, 0, stream>>>(x, pos, out, accf, accu, n, nblocks);
}

// Round 5
// 188.359 us; speedup vs baseline: 1.1432x; 1.1432x over previous
//
#include <hip/hip_runtime.h>
#include <math.h>

#define D 2048
#define EPS_COS 1e-8f
#define EPS_DEN 1e-6f
#define INV_TEMP 10.0f
#define TPB 256
#define WPB 4                   // waves per block, 1 row per wave
#define NBLK 4096               // 4096 blocks * 4 rows = 16384 rows

// pos_pair: reference declares int64 but JAX x64-off makes it int32.
// Hedge: accept int32 reading iff plausible (in range, i != j), else int64.
__device__ __forceinline__ void get_ij(const int* __restrict__ p, int n,
                                       int& i, int& j) {
    int i32 = p[0], j32 = p[1];
    if (i32 >= 0 && i32 < n && j32 >= 0 && j32 < n && i32 != j32) {
        i = i32; j = j32; return;
    }
    const long long* p64 = (const long long*)p;
    i = (int)p64[0]; j = (int)p64[1];
}

// Kernel 1: one row per wave. ALL 16 loads (8 row + 8 xi) issue before any
// dependent math (R3 serialized row loads behind the xi-norm reduce).
// Emits per-block partial denominator (i-row excluded) + e[j] to a slot.
__global__ __launch_bounds__(TPB)
void e_kernel(const float* __restrict__ x, const int* __restrict__ pos,
              float* __restrict__ part, float* __restrict__ nom, int n) {
    int i, j;
    get_ij(pos, n, i, j);
    const int lane = threadIdx.x & 63;
    const int wave = threadIdx.x >> 6;
    const int row  = blockIdx.x * WPB + wave;

    const float4* __restrict__ xr = (const float4*)(x + (size_t)row * D);
    const float4* __restrict__ xi = (const float4*)(x + (size_t)i * D);

    // issue everything first: 16 float4 loads in flight per lane
    float4 a[8], b[8];
#pragma unroll
    for (int w = 0; w < 8; ++w) a[w] = xr[lane + w * 64];
#pragma unroll
    for (int w = 0; w < 8; ++w) b[w] = xi[lane + w * 64];

    float dot = 0.f, sq = 0.f, sqi = 0.f;
#pragma unroll
    for (int w = 0; w < 8; ++w) {
        dot = fmaf(a[w].x, b[w].x, fmaf(a[w].y, b[w].y,
              fmaf(a[w].z, b[w].z, fmaf(a[w].w, b[w].w, dot))));
        sq  = fmaf(a[w].x, a[w].x, fmaf(a[w].y, a[w].y,
              fmaf(a[w].z, a[w].z, fmaf(a[w].w, a[w].w, sq))));
        sqi = fmaf(b[w].x, b[w].x, fmaf(b[w].y, b[w].y,
              fmaf(b[w].z, b[w].z, fmaf(b[w].w, b[w].w, sqi))));
    }
#pragma unroll
    for (int off = 32; off; off >>= 1) {
        dot += __shfl_down(dot, off);
        sq  += __shfl_down(sq,  off);
        sqi += __shfl_down(sqi, off);
    }

    __shared__ float s_den[WPB];
    if (lane == 0) {
        float nk = fmaxf(sqrtf(sq),  EPS_COS);
        float ni = fmaxf(sqrtf(sqi), EPS_COS);
        float e  = expf(INV_TEMP * dot / (nk * ni));
        s_den[wave] = (row != i) ? e : 0.f;   // den includes k==j, excludes k==i
        if (row == j) *nom = e;
    }
    __syncthreads();
    if (threadIdx.x == 0)
        part[blockIdx.x] = (s_den[0] + s_den[1]) + (s_den[2] + s_den[3]);
}

// Kernel 2: one block sums 4096 partials (16 KB) + reads nom, finishes loss.
__global__ __launch_bounds__(1024)
void loss_kernel(const float* __restrict__ part, const float* __restrict__ nom,
                 float* __restrict__ out) {
    const int t = threadIdx.x;
    const float4 v = ((const float4*)part)[t];     // 1024 float4 = 4096 floats
    float s = (v.x + v.y) + (v.z + v.w);
#pragma unroll
    for (int off = 32; off; off >>= 1) s += __shfl_down(s, off);

    __shared__ float ls[16];
    if ((t & 63) == 0) ls[t >> 6] = s;
    __syncthreads();

    if (t == 0) {
        float den = 0.f;
#pragma unroll
        for (int w = 0; w < 16; ++w) den += ls[w];
        out[0] = -logf(nom[0] / (den + EPS_DEN));
    }
}

extern "C" void kernel_launch(void* const* d_in, const int* in_sizes, int n_in,
                              void* d_out, int out_size, void* d_ws, size_t ws_size,
                              hipStream_t stream) {
    const float* x    = (const float*)d_in[0];
    const int*   pos  = (const int*)d_in[1];
    float*       out  = (float*)d_out;
    float*       part = (float*)d_ws;              // [0..4095] block partials
    float*       nom  = (float*)d_ws + NBLK;       // [4096] e_j slot

    const int n = in_sizes[0] / D;                 // 16384

    e_kernel<<<NBLK, TPB, 0, stream>>>(x, pos, part, nom, n);
    loss_kernel<<<1, 1024, 0, stream>>>(part, nom, out);
}